// Round 8
// baseline (463.162 us; speedup 1.0000x reference)
//
#include <hip/hip_runtime.h>
#include <hip/hip_bf16.h>
#include <stdint.h>

#define N_NODES   50000
#define N_EDGES   800000
#define D_MODEL   64
#define D_HIDDEN  256
#define N_GRAPHS  64
#define EPS_GN    1e-5f

#define NBINS_PAD 50176            // 1024 * 49, zero-padded histogram

typedef __attribute__((ext_vector_type(8))) short short8;   // 8 bf16 (4 VGPRs)
typedef __attribute__((ext_vector_type(4))) float f32x4;
typedef __attribute__((ext_vector_type(4))) float float4v;
typedef __attribute__((ext_vector_type(2))) unsigned int uint2v;
typedef __attribute__((ext_vector_type(4))) unsigned int uint4v;
typedef __attribute__((ext_vector_type(4))) int int4v;

static __device__ __forceinline__ short f2bf(float f) {
  union { float f; uint32_t u; } v; v.f = f;
  uint32_t r = (v.u + 0x7fffu + ((v.u >> 16) & 1u)) >> 16;   // RNE
  return (short)(uint16_t)r;
}

// pack two fp32 -> bf16x2 (RNE), hi16 extraction fused via v_perm_b32
static __device__ __forceinline__ uint32_t pack_bf16x2(float lo, float hi) {
  union { float f; uint32_t u; } a, b;
  a.f = lo; b.f = hi;
  uint32_t ra = a.u + 0x7fffu + ((a.u >> 16) & 1u);
  uint32_t rb = b.u + 0x7fffu + ((b.u >> 16) & 1u);
  return __builtin_amdgcn_perm(rb, ra, 0x07060302u);  // {rb.b3,rb.b2,ra.b3,ra.b2}
}

// fast silu: hardware rcp (rel err ~2^-22 << bf16 rounding) instead of IEEE div
static __device__ __forceinline__ float silu_f(float x) {
  return x * __builtin_amdgcn_rcpf(1.0f + __expf(-x));
}

static __device__ __forceinline__ f32x4 mfma16(short8 a, short8 b, f32x4 c) {
  return __builtin_amdgcn_mfma_f32_16x16x32_bf16(a, b, c, 0, 0, 0);
}

// ---------------------------------------------------------------------------
// prep_all: weight frag prep + h->bf16 + ALL workspace zeroing (replaces the
// 3 hipMemsetAsync graph nodes; each serialized graph node costs ~10-18 us).
// Block ranges: [0,52) weights | [52,1615) h_bf | [1615,4740) zero agg |
// [4740,4789) zero hist | [4789,4798) zero s1/s2/cnt.
// ---------------------------------------------------------------------------
#define PREP_TOTAL 4798

__global__ void prep_all(const float* __restrict__ mw1, const float* __restrict__ mw2,
                         const float* __restrict__ uw1, const float* __restrict__ uw2,
                         const float* __restrict__ h,
                         short* __restrict__ w1f, short* __restrict__ w2f,
                         short* __restrict__ u1f, short* __restrict__ u2f,
                         short* __restrict__ h_bf,
                         float* __restrict__ agg, int* __restrict__ hist,
                         float* __restrict__ stats) {
  int b = blockIdx.x;
  if (b >= 4789) {                     // zero s1/s2/cnt (contiguous 33024 B)
    int i = (b - 4789) * 256 + threadIdx.x;
    if (i < 2064) ((float4v*)stats)[i] = (float4v){0.f, 0.f, 0.f, 0.f};
    return;
  }
  if (b >= 4740) {                     // zero hist (50176 ints)
    int i = (b - 4740) * 256 + threadIdx.x;
    if (i < 12544) ((int4v*)hist)[i] = (int4v){0, 0, 0, 0};
    return;
  }
  if (b >= 1615) {                     // zero agg (3.2M floats)
    int i = (b - 1615) * 256 + threadIdx.x;
    if (i < 800000) ((float4v*)agg)[i] = (float4v){0.f, 0.f, 0.f, 0.f};
    return;
  }
  if (b >= 52) {                       // h -> bf16, 8 elems/thread
    int t2 = (b - 52) * 256 + threadIdx.x;
    if (t2 < N_NODES * D_MODEL / 8) {
      const float4v* src = (const float4v*)(h + (size_t)t2 * 8);
      float4v v0 = src[0], v1 = src[1];
      uint4v p = {pack_bf16x2(v0.x, v0.y), pack_bf16x2(v0.z, v0.w),
                  pack_bf16x2(v1.x, v1.y), pack_bf16x2(v1.z, v1.w)};
      *(uint4v*)(h_bf + (size_t)t2 * 8) = p;
    }
    return;
  }
  const float* w; short* out; int K, Nn, t;
  if (b < 20)      { w = mw1; out = w1f; K = 160; Nn = 256; t = b * 256 + threadIdx.x; }
  else if (b < 28) { w = mw2; out = w2f; K = 256; Nn = 64;  t = (b - 20) * 256 + threadIdx.x; }
  else if (b < 44) { w = uw1; out = u1f; K = 128; Nn = 256; t = (b - 28) * 256 + threadIdx.x; }
  else             { w = uw2; out = u2f; K = 256; Nn = 64;  t = (b - 44) * 256 + threadIdx.x; }
  int total = (K >> 5) * (Nn >> 4) * 64;
  if (t >= total) return;
  int lane = t & 63;
  int rest = t >> 6;
  int ntN = Nn >> 4;
  int nt = rest % ntN;
  int kt = rest / ntN;
  int n  = nt * 16 + (lane & 15);
  int k0 = kt * 32 + (lane >> 4) * 8;
  short* o = out + (size_t)t * 8;
#pragma unroll
  for (int j = 0; j < 8; ++j)
    o[j] = f2bf(w[(size_t)(k0 + j) * Nn + n]);
}

// ---------------------------------------------------------------------------
// Counting sort by dst: hist -> single-block full scan -> scatter. 3 kernels.
// ---------------------------------------------------------------------------
__global__ __launch_bounds__(256)
void hist_k(const int* __restrict__ ei, int* __restrict__ hist) {
  int e = blockIdx.x * 256 + threadIdx.x;
  if (e >= N_EDGES) return;
  atomicAdd(&hist[ei[N_EDGES + e]], 1);
}

// one block, 1024 threads: each thread serial-scans 49 bins; Hillis-Steele
// across thread totals; write final global exclusive offsets.
__global__ __launch_bounds__(1024)
void scan_all(const int* __restrict__ hist, int* __restrict__ offs) {
  __shared__ int sc[1024];
  const int t = threadIdx.x;
  const int base = t * 49;
  int s = 0;
  for (int i = 0; i < 49; ++i) s += hist[base + i];
  sc[t] = s;
  __syncthreads();
#pragma unroll
  for (int d = 1; d < 1024; d <<= 1) {
    int v = (t >= d) ? sc[t - d] : 0;
    __syncthreads();
    sc[t] += v;
    __syncthreads();
  }
  int run = sc[t] - s;                 // exclusive prefix of this chunk
  for (int i = 0; i < 49; ++i) {
    int hv = hist[base + i];
    offs[base + i] = run;
    run += hv;
  }
}

__global__ __launch_bounds__(256)
void scatter_k(const int* __restrict__ ei, int* __restrict__ offs,
               int* __restrict__ sorted) {
  int e = blockIdx.x * 256 + threadIdx.x;
  if (e >= N_EDGES) return;
  int d = ei[N_EDGES + e];
  int pos = atomicAdd(&offs[d], 1);
  sorted[pos] = e;
}

// ---------------------------------------------------------------------------
// Edge MLP — block-cooperative, 64 dst-sorted edges / block. (unchanged R7)
// ---------------------------------------------------------------------------
#define LDA_E 168   // 160 + 8 pad shorts; row = 336 B (16B aligned)
#define LDH   264   // 256 + 8 pad shorts; row = 528 B (16B aligned)
#define LDC   68    // fp32 stride of C tile

__global__ __launch_bounds__(256, 2)
void edge_mlp(const short* __restrict__ h_bf, const float* __restrict__ ea,
              const int* __restrict__ ei, const int* __restrict__ sorted,
              const short* __restrict__ w1f, const float* __restrict__ b1,
              const short* __restrict__ w2f, const float* __restrict__ b2,
              float* __restrict__ agg) {
  __shared__ __align__(16) short buf[64 * LDH];    // sA [64][LDA_E] then sH
  __shared__ __align__(16) float sC[64 * LDC];     // 17408 B
  __shared__ int s_ids[4][48];                     // src[16], dst[16], eid[16]

  const int tid  = threadIdx.x;
  const int lane = tid & 63;
  const int wave = tid >> 6;
  const int col  = lane & 15;
  const int quad = lane >> 4;
  const int eb   = blockIdx.x * 64 + wave * 16;    // this wave's 16 sorted slots
  short* sA = buf;
  short* sH = buf;

  // ---- resolve sorted edge ids -> src/dst/eid (wave-local)
  if (lane < 48) {
    int i15 = lane & 15;
    int e0 = sorted[eb + i15];
    int v;
    if (lane < 16)      v = ei[e0];
    else if (lane < 32) v = ei[N_EDGES + e0];
    else                v = e0;
    s_ids[wave][lane] = v;
  }

  // ---- stage h_dst | h_src rows (bf16 copy, no conversion)
#pragma unroll
  for (int it = 0; it < 2; ++it) {
    int idx = it * 64 + lane;        // 0..127
    int e = idx >> 3, c = idx & 7;
    int row = wave * 16 + e;
    int d = s_ids[wave][16 + e];
    int s = s_ids[wave][e];
    *(short8*)&sA[row * LDA_E + c * 8] =
        *(const short8*)(h_bf + (size_t)d * D_MODEL + c * 8);
    *(short8*)&sA[row * LDA_E + 64 + c * 8] =
        *(const short8*)(h_bf + (size_t)s * D_MODEL + c * 8);
  }
  // ---- stage edge_attr (fp32 -> packed bf16)
#pragma unroll
  for (int it = 0; it < 2; ++it) {
    int idx = it * 64 + lane;        // 0..127
    int e = idx >> 3, j = idx & 7;
    int row = wave * 16 + e;
    int eid = s_ids[wave][32 + e];
    float4v v = *(const float4v*)(ea + (size_t)eid * 32 + j * 4);
    uint2v p = {pack_bf16x2(v.x, v.y), pack_bf16x2(v.z, v.w)};
    *(uint2v*)&sA[row * LDA_E + 128 + j * 4] = p;
  }
  __syncthreads();                                  // b1: sA visible

  // ---- GEMM1: [64,160] x [160,256]; wave covers n-tiles [4w, 4w+4)
  f32x4 acc[4][4];
#pragma unroll
  for (int mt = 0; mt < 4; ++mt)
#pragma unroll
    for (int nt = 0; nt < 4; ++nt)
      acc[mt][nt] = (f32x4){0.f, 0.f, 0.f, 0.f};

  short8 bf[2][4];
#pragma unroll
  for (int nt = 0; nt < 4; ++nt)
    bf[0][nt] = *(const short8*)(w1f + (size_t)((wave * 4 + nt) * 64 + lane) * 8);

#pragma unroll
  for (int kt = 0; kt < 5; ++kt) {
    if (kt < 4) {
#pragma unroll
      for (int nt = 0; nt < 4; ++nt)
        bf[(kt + 1) & 1][nt] = *(const short8*)(
            w1f + (size_t)(((kt + 1) * 16 + wave * 4 + nt) * 64 + lane) * 8);
    }
    short8 af[4];
#pragma unroll
    for (int mt = 0; mt < 4; ++mt)
      af[mt] = *(const short8*)&sA[(mt * 16 + col) * LDA_E + kt * 32 + quad * 8];
#pragma unroll
    for (int nt = 0; nt < 4; ++nt)
#pragma unroll
      for (int mt = 0; mt < 4; ++mt)
        acc[mt][nt] = mfma16(af[mt], bf[kt & 1][nt], acc[mt][nt]);
  }
  __syncthreads();                                  // b2: sA dead, safe to reuse

  // ---- bias + silu -> sH (wave writes its 64-col slice, all 64 rows)
#pragma unroll
  for (int nt = 0; nt < 4; ++nt) {
    const int n = (wave * 4 + nt) * 16 + col;
    const float bias = b1[n];
#pragma unroll
    for (int mt = 0; mt < 4; ++mt) {
#pragma unroll
      for (int r = 0; r < 4; ++r) {
        const int row = mt * 16 + quad * 4 + r;
        sH[row * LDH + n] = f2bf(silu_f(acc[mt][nt][r] + bias));
      }
    }
  }
  __syncthreads();                                  // b3: sH visible

  // ---- GEMM2: [64,256] x [256,64]; wave covers n-tile `wave` (16 cols)
  f32x4 acc2[4];
#pragma unroll
  for (int mt = 0; mt < 4; ++mt) acc2[mt] = (f32x4){0.f, 0.f, 0.f, 0.f};

  short8 bf2[2];
  bf2[0] = *(const short8*)(w2f + (size_t)(wave * 64 + lane) * 8);

#pragma unroll
  for (int kt = 0; kt < 8; ++kt) {
    if (kt < 7)
      bf2[(kt + 1) & 1] = *(const short8*)(
          w2f + (size_t)(((kt + 1) * 4 + wave) * 64 + lane) * 8);
    short8 af[4];
#pragma unroll
    for (int mt = 0; mt < 4; ++mt)
      af[mt] = *(const short8*)&sH[(mt * 16 + col) * LDH + kt * 32 + quad * 8];
#pragma unroll
    for (int mt = 0; mt < 4; ++mt)
      acc2[mt] = mfma16(af[mt], bf2[kt & 1], acc2[mt]);
  }

  // ---- dump C (+bias) into separate sC tile
  {
    const int n = wave * 16 + col;
    const float bias = b2[n];
#pragma unroll
    for (int mt = 0; mt < 4; ++mt)
#pragma unroll
      for (int r = 0; r < 4; ++r)
        sC[(mt * 16 + quad * 4 + r) * LDC + n] = acc2[mt][r] + bias;
  }
  __syncthreads();                                  // b4: sC visible

  // ---- run-reduce own 16 rows (dst-sorted): one atomic per run per feature
  float sum = 0.f;
  int prev = s_ids[wave][16];
#pragma unroll
  for (int r = 0; r < 16; ++r) {
    float v = sC[(wave * 16 + r) * LDC + lane];
    int d = s_ids[wave][16 + r];          // LDS broadcast -> wave-uniform
    if (d != prev) {
      atomicAdd(agg + (size_t)prev * D_MODEL + lane, sum);
      sum = 0.f; prev = d;
    }
    sum += v;
  }
  atomicAdd(agg + (size_t)prev * D_MODEL + lane, sum);
}

// ---------------------------------------------------------------------------
// Node MLP — block-cooperative, 64 nodes / block, fused GraphNorm stats.
// ---------------------------------------------------------------------------
#define LDA_N 136   // 128 + 8 pad shorts; row = 272 B (16B aligned)

__global__ __launch_bounds__(256, 2)
void node_mlp(const float* __restrict__ h, const short* __restrict__ h_bf,
              const float* __restrict__ agg,
              const short* __restrict__ w1f, const float* __restrict__ b1,
              const short* __restrict__ w2f, const float* __restrict__ b2,
              const int* __restrict__ batch,
              float* __restrict__ hnew,
              float* __restrict__ s1, float* __restrict__ s2,
              float* __restrict__ cnt) {
  __shared__ __align__(16) short buf[64 * LDH];    // sA [64][LDA_N] then sH
  __shared__ int s_b[64];                          // batch ids of block rows

  const int tid  = threadIdx.x;
  const int lane = tid & 63;
  const int wave = tid >> 6;
  const int col  = lane & 15;
  const int quad = lane >> 4;
  const int nb   = blockIdx.x * 64;
  short* sA = buf;
  short* sH = buf;

  if (tid < 64) {
    int gi = nb + tid;
    s_b[tid] = batch[(gi < N_NODES) ? gi : (N_NODES - 1)];
  }

  // ---- stage h rows (bf16 copy)
#pragma unroll
  for (int it = 0; it < 2; ++it) {
    int idx = it * 64 + lane;     // 0..127
    int i = idx >> 3, c = idx & 7;
    int row = wave * 16 + i;
    int gi = nb + row;
    if (gi >= N_NODES) gi = N_NODES - 1;
    *(short8*)&sA[row * LDA_N + c * 8] =
        *(const short8*)(h_bf + (size_t)gi * D_MODEL + c * 8);
  }
  // ---- stage agg rows (fp32 -> packed bf16)
#pragma unroll
  for (int it = 0; it < 4; ++it) {
    int idx = it * 64 + lane;     // 0..255
    int i = idx >> 4, j = idx & 15;
    int row = wave * 16 + i;
    int gi = nb + row;
    if (gi >= N_NODES) gi = N_NODES - 1;
    float4v v = *(const float4v*)(agg + (size_t)gi * D_MODEL + j * 4);
    uint2v p = {pack_bf16x2(v.x, v.y), pack_bf16x2(v.z, v.w)};
    *(uint2v*)&sA[row * LDA_N + 64 + j * 4] = p;
  }
  __syncthreads();                                  // b1

  // ---- per-graph node counts (one wave; ballot run-length over 64 rows)
  if (wave == 3) {
    int gi = nb + lane;
    bool valid = gi < N_NODES;
    int g = s_b[lane];
    int gp = __shfl_up(g, 1);
    bool start = valid && (lane == 0 || g != gp);
    unsigned long long bmask = __ballot(start);
    unsigned long long imask = __ballot(!valid);
    if (start) {
      unsigned long long higher =
          (lane == 63) ? 0ULL : (((bmask | imask) >> (lane + 1)) << (lane + 1));
      int next = higher ? (__ffsll((long long)higher) - 1) : 64;
      atomicAdd(&cnt[g], (float)(next - lane));
    }
  }

  // ---- GEMM1: K=128; wave covers n-tiles [4w, 4w+4)
  f32x4 acc[4][4];
#pragma unroll
  for (int mt = 0; mt < 4; ++mt)
#pragma unroll
    for (int nt = 0; nt < 4; ++nt)
      acc[mt][nt] = (f32x4){0.f, 0.f, 0.f, 0.f};

  short8 bf[2][4];
#pragma unroll
  for (int nt = 0; nt < 4; ++nt)
    bf[0][nt] = *(const short8*)(w1f + (size_t)((wave * 4 + nt) * 64 + lane) * 8);

#pragma unroll
  for (int kt = 0; kt < 4; ++kt) {
    if (kt < 3) {
#pragma unroll
      for (int nt = 0; nt < 4; ++nt)
        bf[(kt + 1) & 1][nt] = *(const short8*)(
            w1f + (size_t)(((kt + 1) * 16 + wave * 4 + nt) * 64 + lane) * 8);
    }
    short8 af[4];
#pragma unroll
    for (int mt = 0; mt < 4; ++mt)
      af[mt] = *(const short8*)&sA[(mt * 16 + col) * LDA_N + kt * 32 + quad * 8];
#pragma unroll
    for (int nt = 0; nt < 4; ++nt)
#pragma unroll
      for (int mt = 0; mt < 4; ++mt)
        acc[mt][nt] = mfma16(af[mt], bf[kt & 1][nt], acc[mt][nt]);
  }
  __syncthreads();                                  // b2: sA dead

#pragma unroll
  for (int nt = 0; nt < 4; ++nt) {
    const int n = (wave * 4 + nt) * 16 + col;
    const float bias = b1[n];
#pragma unroll
    for (int mt = 0; mt < 4; ++mt) {
#pragma unroll
      for (int r = 0; r < 4; ++r) {
        const int row = mt * 16 + quad * 4 + r;
        sH[row * LDH + n] = f2bf(silu_f(acc[mt][nt][r] + bias));
      }
    }
  }
  __syncthreads();                                  // b3: sH visible

  // ---- GEMM2: K=256; wave covers n-tile `wave`
  f32x4 acc2[4];
#pragma unroll
  for (int mt = 0; mt < 4; ++mt) acc2[mt] = (f32x4){0.f, 0.f, 0.f, 0.f};

  short8 bf2[2];
  bf2[0] = *(const short8*)(w2f + (size_t)(wave * 64 + lane) * 8);

#pragma unroll
  for (int kt = 0; kt < 8; ++kt) {
    if (kt < 7)
      bf2[(kt + 1) & 1] = *(const short8*)(
          w2f + (size_t)(((kt + 1) * 4 + wave) * 64 + lane) * 8);
    short8 af[4];
#pragma unroll
    for (int mt = 0; mt < 4; ++mt)
      af[mt] = *(const short8*)&sH[(mt * 16 + col) * LDH + kt * 32 + quad * 8];
#pragma unroll
    for (int mt = 0; mt < 4; ++mt)
      acc2[mt] = mfma16(af[mt], bf2[kt & 1], acc2[mt]);
  }

  // ---- epilogue: h_new = h + dh -> global, fused per-lane run-reduce of
  // s1/s2 over this lane's 16 ascending rows of the sorted batch.
  {
    const int n = wave * 16 + col;
    const float bias = b2[n];
    float a1 = 0.f, a2 = 0.f;
    int prev = s_b[quad * 4];     // lane's first row (mt=0, r=0)
#pragma unroll
    for (int mt = 0; mt < 4; ++mt) {
#pragma unroll
      for (int r = 0; r < 4; ++r) {
        const int row = mt * 16 + quad * 4 + r;
        const int gi = nb + row;
        const bool valid = gi < N_NODES;
        int g = s_b[row];
        if (g != prev) {
          atomicAdd(&s1[prev * D_MODEL + n], a1);
          atomicAdd(&s2[prev * D_MODEL + n], a2);
          a1 = 0.f; a2 = 0.f; prev = g;
        }
        if (valid) {
          float hv = h[(size_t)gi * D_MODEL + n] + acc2[mt][r] + bias;
          hnew[(size_t)gi * D_MODEL + n] = hv;
          a1 += hv; a2 += hv * hv;
        }
      }
    }
    atomicAdd(&s1[prev * D_MODEL + n], a1);
    atomicAdd(&s2[prev * D_MODEL + n], a2);
  }
}

// ---------------------------------------------------------------------------
// GraphNorm normalize (stats already produced by node_mlp).
// ---------------------------------------------------------------------------
__global__ __launch_bounds__(256)
void gn_norm(float* __restrict__ x, const int* __restrict__ batch,
             const float* __restrict__ s1, const float* __restrict__ s2,
             const float* __restrict__ cnt, const float* __restrict__ alpha,
             const float* __restrict__ weight, const float* __restrict__ bias) {
  int idx = blockIdx.x * 256 + threadIdx.x;
  if (idx >= N_NODES * D_MODEL) return;
  int i = idx >> 6, f = idx & 63;
  int g = batch[i];
  float c = fmaxf(cnt[g], 1.f);
  float m   = s1[g * D_MODEL + f] / c;
  float ex2 = s2[g * D_MODEL + f] / c;
  float a = alpha[f];
  float var = ex2 - 2.f * a * m * m + a * a * m * m;
  float hc = x[idx] - a * m;
  x[idx] = weight[f] * hc * rsqrtf(var + EPS_GN) + bias[f];
}

// ---------------------------------------------------------------------------
extern "C" void kernel_launch(void* const* d_in, const int* in_sizes, int n_in,
                              void* d_out, int out_size, void* d_ws, size_t ws_size,
                              hipStream_t stream) {
  const float* h     = (const float*)d_in[0];
  const float* ea    = (const float*)d_in[1];
  const int*   ei    = (const int*)d_in[2];   // [2][E], row0=src, row1=dst
  const int*   batch = (const int*)d_in[3];
  const float* mw1   = (const float*)d_in[4];
  const float* mb1   = (const float*)d_in[5];
  const float* mw2   = (const float*)d_in[6];
  const float* mb2   = (const float*)d_in[7];
  const float* uw1   = (const float*)d_in[8];
  const float* ub1   = (const float*)d_in[9];
  const float* uw2   = (const float*)d_in[10];
  const float* ub2   = (const float*)d_in[11];
  const float* gw    = (const float*)d_in[12];
  const float* gb    = (const float*)d_in[13];
  const float* ga    = (const float*)d_in[14];

  char* ws = (char*)d_ws;
  float* agg    = (float*)(ws + 0);             // 12,800,000 B
  short* w1f    = (short*)(ws + 12800000);      //     81,920 B
  short* w2f    = (short*)(ws + 12881920);      //     32,768 B
  short* u1f    = (short*)(ws + 12914688);      //     65,536 B
  short* u2f    = (short*)(ws + 12980224);      //     32,768 B
  float* s1     = (float*)(ws + 13012992);      //     16,384 B
  float* s2     = (float*)(ws + 13029376);      //     16,384 B
  float* cnt    = (float*)(ws + 13045760);      //        256 B (+pad to 33024)
  int*   hist   = (int*)  (ws + 13046016);      //    200,704 B (50176 ints)
  int*   offs   = (int*)  (ws + 13246720);      //    200,704 B
  int*   sorted = (int*)  (ws + 13449472);      //  3,200,000 B
  short* h_bf   = (short*)(ws + 16649472);      //  6,400,000 B -> end 23,049,472

  // 7 serialized graph nodes total (was 14): prep(+all zeroing), hist, scan,
  // scatter, edge, node, norm.
  prep_all<<<PREP_TOTAL, 256, 0, stream>>>(mw1, mw2, uw1, uw2, h,
                                           w1f, w2f, u1f, u2f, h_bf,
                                           agg, hist, s1);

  hist_k   <<<(N_EDGES + 255) / 256, 256, 0, stream>>>(ei, hist);
  scan_all <<<1, 1024, 0, stream>>>(hist, offs);
  scatter_k<<<(N_EDGES + 255) / 256, 256, 0, stream>>>(ei, offs, sorted);

  edge_mlp<<<N_EDGES / 64, 256, 0, stream>>>(h_bf, ea, ei, sorted,
                                             w1f, mb1, w2f, mb2, agg);

  node_mlp<<<(N_NODES + 63) / 64, 256, 0, stream>>>(h, h_bf, agg,
                                                    u1f, ub1, u2f, ub2,
                                                    batch, (float*)d_out,
                                                    s1, s2, cnt);

  gn_norm<<<(N_NODES * D_MODEL + 255) / 256, 256, 0, stream>>>(
      (float*)d_out, batch, s1, s2, cnt, ga, gw, gb);
}